// Round 15
// baseline (70.946 us; speedup 1.0000x reference)
//
#include <hip/hip_runtime.h>
#include <hip/hip_bf16.h>
#include <stdint.h>

#define S_LEN 4096
#define DK    64
#define BQ    64
#define BK    64

typedef __bf16 bf16x8  __attribute__((ext_vector_type(8)));
typedef float  f32x16  __attribute__((ext_vector_type(16)));

__device__ __forceinline__ short f2bf(float f) {
    union { __bf16 h; short s; } u; u.h = (__bf16)f; return u.s;
}
__device__ __forceinline__ short4 cvt4(float4 f) {
    short4 s; s.x = f2bf(f.x); s.y = f2bf(f.y); s.z = f2bf(f.z); s.w = f2bf(f.w); return s;
}

__device__ __forceinline__ uint32_t cvtpk_bf16(float lo, float hi) {
    uint32_t d;
    asm("v_cvt_pk_bf16_f32 %0, %1, %2" : "=&v"(d) : "v"(lo), "v"(hi));
    return d;
}
__device__ __forceinline__ void plswap(uint32_t& a, uint32_t& b) {
    asm("v_permlane32_swap_b32 %0, %1" : "+v"(a), "+v"(b));
}

// global -> LDS direct 16B/lane (LDS dest = wave-uniform base + lane*16).
__device__ __forceinline__ void gload_lds16(const void* g, void* l) {
    auto gp = reinterpret_cast<const uint32_t __attribute__((address_space(1)))*>(
        reinterpret_cast<uintptr_t>(g));
    auto lp = reinterpret_cast<uint32_t __attribute__((address_space(3)))*>(
        reinterpret_cast<uintptr_t>(l));
    __builtin_amdgcn_global_load_lds(gp, lp, 16, 0, 0);
}

// conflict-free chunk swizzle: rows {j,j+8,j+16,j+24} land on distinct chunks
__device__ __forceinline__ int swz(int row) {
    return ((row ^ (row >> 3)) & 7) << 3;
}

// ---- prep: K -> bf16 swizzled [b][tile][row][col^swz]; V -> bf16 transposed
// [b][tile][d][key^swz]. One (b,tile) per block.
__global__ __launch_bounds__(256) void prep_kernel(
    const float* __restrict__ K, const float* __restrict__ V,
    short* __restrict__ WK, short* __restrict__ WV)
{
    const int t = blockIdx.x, b = blockIdx.y;
    const int tid = threadIdx.x;
    const size_t ibase = ((size_t)b * S_LEN + (size_t)t * 64) * DK;
    const size_t obase = ((size_t)b * 64 + t) * 4096;
    const int r0 = tid >> 4;          // 0..15
    const int c0 = (tid & 15) * 4;    // 0..60

    #pragma unroll
    for (int i = 0; i < 4; ++i) {
        const int row = r0 + 16 * i;
        const float4 f = *reinterpret_cast<const float4*>(K + ibase + (size_t)row * DK + c0);
        *reinterpret_cast<short4*>(WK + obase + row * 64 + (c0 ^ swz(row))) = cvt4(f);
    }
    float4 vf[4];
    #pragma unroll
    for (int j = 0; j < 4; ++j)
        vf[j] = *reinterpret_cast<const float4*>(V + ibase + (size_t)(4 * r0 + j) * DK + c0);
    #pragma unroll
    for (int jj = 0; jj < 4; ++jj) {
        const int d = c0 + jj;
        short4 sp;
        sp.x = f2bf(reinterpret_cast<const float*>(&vf[0])[jj]);
        sp.y = f2bf(reinterpret_cast<const float*>(&vf[1])[jj]);
        sp.z = f2bf(reinterpret_cast<const float*>(&vf[2])[jj]);
        sp.w = f2bf(reinterpret_cast<const float*>(&vf[3])[jj]);
        *reinterpret_cast<short4*>(WV + obase + d * 64 + ((4 * r0) ^ swz(d))) = sp;
    }
}

// ---- main: flash attention, causal, scale=1/64 * log2(e) (exp2 domain).
// 256 blocks x 1024 threads (16 waves = 4 grp x 2 khalf x 2 qsub).
// Each wave computes a 32-key HALF of its grp's tile -> 4 independent
// half-size chains per SIMD (TLP hides the serial softmax chain).
// m_run floor is FINITE (-1e38, not -inf): a fully-masked key-half on a
// wave's first tile would otherwise produce exp2(-inf - -inf) = NaN (R14 bug).
__global__ __launch_bounds__(1024, 4) void attn_kernel(
    const float* __restrict__ Q, float* __restrict__ O,
    const short* __restrict__ WK, const short* __restrict__ WV)
{
    __shared__ __align__(16) short Ks[2][16384];   // [buf][tile*4096 + row*64 + col^swz]
    __shared__ __align__(16) short Vts[2][16384];  // [buf][tile*4096 + d*64 + key^swz]
    __shared__ float2 Ml[8][2][32];                // [role][qsub][qrow] {m,l} (log2)

    const int tid  = threadIdx.x;
    const int wave = tid >> 6;
    const int lane = tid & 63;
    const int q32  = lane & 31;
    const int hi   = lane >> 5;
    const int hi4  = hi * 4;
    const int hi8  = hi * 8;
    const int grp   = wave & 3;        // key-split group: tile 4p+grp
    const int khalf = (wave >> 2) & 1; // 32-key half within the tile
    const int qsub  = wave >> 3;       // 32-row q sub-tile
    const int role  = grp * 2 + khalf; // 0..7 (merge partial id)

    const int batch = blockIdx.y;
    const size_t bo = (size_t)batch * S_LEN * DK;
    const short* WKb = WK + (size_t)batch * 262144;
    const short* WVb = WV + (size_t)batch * 262144;

    auto stage_quad = [&](int quad, int buf) {
        const char* gk = (const char*)(WKb + (size_t)quad * 16384) + tid * 16;
        const char* gv = (const char*)(WVb + (size_t)quad * 16384) + tid * 16;
        char* lk = (char*)(&Ks[buf][0]) + tid * 16;
        char* lv = (char*)(&Vts[buf][0]) + tid * 16;
        #pragma unroll
        for (int i = 0; i < 2; ++i) {
            gload_lds16(gk + i * 16384, lk + i * 16384);
            gload_lds16(gv + i * 16384, lv + i * 16384);
        }
    };

    const float NEG_INF = -__builtin_inff();
    const float MFLOOR  = -1e38f;                            // finite m sentinel
    const float QSCALE  = 0.015625f * 1.44269504088896341f;  // 1/64 * log2(e)
    const float THR     = 8.0f;                              // T13, log2 domain
    const int swzK  = swz(32 * khalf + q32);  // K row this wave reads
    const int swzV0 = swz(q32);               // V^T rows (d = q32, 32+q32)
    const int swzV1 = swz(32 + q32);

    #pragma unroll 1
    for (int qi = 0; qi < 2; ++qi) {
        const int qb = qi ? (int)blockIdx.x : 63 - (int)blockIdx.x;
        const int q0 = qb * BQ;
        const int ntiles = qb + 1;
        const int nquads = (ntiles + 3) >> 2;
        const int qrow   = q0 + 32 * qsub + q32;

        // Q fragments (B operand), scale folded
        bf16x8 qf[4];
        {
            const float* Qr = Q + bo + (size_t)qrow * DK;
            #pragma unroll
            for (int s = 0; s < 4; ++s) {
                const float4 a = *reinterpret_cast<const float4*>(Qr + 16 * s + hi8);
                const float4 b = *reinterpret_cast<const float4*>(Qr + 16 * s + hi8 + 4);
                qf[s][0] = (__bf16)(a.x * QSCALE); qf[s][1] = (__bf16)(a.y * QSCALE);
                qf[s][2] = (__bf16)(a.z * QSCALE); qf[s][3] = (__bf16)(a.w * QSCALE);
                qf[s][4] = (__bf16)(b.x * QSCALE); qf[s][5] = (__bf16)(b.y * QSCALE);
                qf[s][6] = (__bf16)(b.z * QSCALE); qf[s][7] = (__bf16)(b.w * QSCALE);
            }
        }

        float m_run = MFLOOR, l_run = 0.f;
        f32x16 oa0, oa1;  // O-partial[q=crow(r,hi)][d = q32 / 32+q32]
        #pragma unroll
        for (int r = 0; r < 16; ++r) { oa0[r] = 0.f; oa1[r] = 0.f; }

        stage_quad(0, 0);
        __syncthreads();

        for (int p = 0; p < nquads; ++p) {
            const int kt = 4 * p + grp;
            const bool pf = (p + 1 < nquads);
            if (pf) stage_quad(p + 1, (p + 1) & 1);  // in flight across compute

            const short* Kt = &Ks[p & 1][grp * 4096];
            const short* Vt = &Vts[p & 1][grp * 4096];

            if (kt < ntiles) {
                // ---- S^T half: lane owns 32 keys (32*khalf..+31) of row q32
                f32x16 sa;
                #pragma unroll
                for (int r = 0; r < 16; ++r) sa[r] = 0.f;
                __builtin_amdgcn_s_setprio(1);
                #pragma unroll
                for (int s = 0; s < 4; ++s) {
                    const int col = 16 * s + hi8;
                    const bf16x8 kf = *reinterpret_cast<const bf16x8*>(
                        &Kt[(32 * khalf + q32) * 64 + (col ^ swzK)]);
                    sa = __builtin_amdgcn_mfma_f32_32x32x16_bf16(kf, qf[s], sa, 0, 0, 0);
                }
                __builtin_amdgcn_s_setprio(0);

                // ---- causal mask (diag tile only) + row max
                float ma[4] = {NEG_INF, NEG_INF, NEG_INF, NEG_INF};
                if (kt == qb) {
                    const int keybase = kt * BK + 32 * khalf + hi4;
                    #pragma unroll
                    for (int r = 0; r < 16; ++r) {
                        const int kl = (r & 3) + 8 * (r >> 2);
                        if (keybase + kl > qrow) sa[r] = NEG_INF;
                        ma[r & 3] = fmaxf(ma[r & 3], sa[r]);
                    }
                } else {
                    #pragma unroll
                    for (int r = 0; r < 16; ++r)
                        ma[r & 3] = fmaxf(ma[r & 3], sa[r]);
                }
                float mt = fmaxf(fmaxf(ma[0], ma[1]), fmaxf(ma[2], ma[3]));
                mt = fmaxf(mt, __shfl_xor(mt, 32));

                // ---- T13: rescale only when max grew past THR.
                // m_run stays finite (>= MFLOOR); masked-only tiles keep it there.
                if (!__all(mt <= m_run + THR)) {
                    const float mnew = fmaxf(m_run, mt);
                    const float alpha = __builtin_amdgcn_exp2f(m_run - mnew);  // underflow -> 0
                    m_run = mnew;
                    l_run *= alpha;
                    #pragma unroll
                    for (int r = 0; r < 16; ++r) {
                        const float ar = __shfl(alpha, (r & 3) + 8 * (r >> 2) + hi4);
                        oa0[r] *= ar; oa1[r] *= ar;
                    }
                }

                // ---- exp2 + partial sum (m_run finite -> -inf inputs give 0, never NaN)
                float pp[4] = {0.f, 0.f, 0.f, 0.f};
                #pragma unroll
                for (int r = 0; r < 16; ++r) {
                    sa[r] = __builtin_amdgcn_exp2f(sa[r] - m_run);
                    pp[r & 3] += sa[r];
                }
                float ps = (pp[0] + pp[1]) + (pp[2] + pp[3]);
                ps += __shfl_xor(ps, 32);
                l_run += ps;

                // ---- PV half (T12 in-register P)
                __builtin_amdgcn_s_setprio(1);
                #pragma unroll
                for (int s2 = 0; s2 < 2; ++s2) {
                    uint32_t a0 = cvtpk_bf16(sa[8*s2+0], sa[8*s2+1]);
                    uint32_t a1 = cvtpk_bf16(sa[8*s2+2], sa[8*s2+3]);
                    uint32_t b0 = cvtpk_bf16(sa[8*s2+4], sa[8*s2+5]);
                    uint32_t b1 = cvtpk_bf16(sa[8*s2+6], sa[8*s2+7]);
                    plswap(a0, b0);
                    plswap(a1, b1);
                    union { uint32_t u[4]; bf16x8 v; } pw;
                    pw.u[0] = a0; pw.u[1] = a1; pw.u[2] = b0; pw.u[3] = b1;
                    const int vcol = 32 * khalf + 16 * s2 + hi8;
                    const bf16x8 vf0 = *reinterpret_cast<const bf16x8*>(&Vt[q32 * 64 + (vcol ^ swzV0)]);
                    const bf16x8 vf1 = *reinterpret_cast<const bf16x8*>(&Vt[(32 + q32) * 64 + (vcol ^ swzV1)]);
                    oa0 = __builtin_amdgcn_mfma_f32_32x32x16_bf16(pw.v, vf0, oa0, 0, 0, 0);
                    oa1 = __builtin_amdgcn_mfma_f32_32x32x16_bf16(pw.v, vf1, oa1, 0, 0, 0);
                }
                __builtin_amdgcn_s_setprio(0);
            }

            __syncthreads();  // reads done + prefetched quad landed
        }

        // ---- 8-way merge. All 16 waves dump O-partials (f32) into retired
        // KV LDS (qsub0 -> Ks, qsub1 -> Vts; role r at offset r*2048 floats),
        // cols XOR-swizzled by row. m,l via Ml. All m values finite.
        if (hi == 0) Ml[role][qsub][q32] = make_float2(m_run, l_run);
        {
            float* Obase = (qsub == 0 ? reinterpret_cast<float*>(&Ks[0][0])
                                      : reinterpret_cast<float*>(&Vts[0][0])) + role * 2048;
            #pragma unroll
            for (int r = 0; r < 16; ++r) {
                const int row = (r & 3) + 8 * (r >> 2) + hi4;
                const int sw  = swz(row);
                Obase[row * 64 + (q32 ^ sw)]        = oa0[r];
                Obase[row * 64 + ((32 + q32) ^ sw)] = oa1[r];
            }
        }
        __syncthreads();
        {
            // wave (role R, qsub s) merges d-slice [8R..8R+8) for its 32 rows
            const float* Mbase = (qsub == 0 ? reinterpret_cast<const float*>(&Ks[0][0])
                                            : reinterpret_cast<const float*>(&Vts[0][0]));
            const int row = lane & 31;
            const int d0  = 8 * role + 4 * hi;
            float mg[8], lg[8];
            #pragma unroll
            for (int g = 0; g < 8; ++g) {
                const float2 v = Ml[g][qsub][row];
                mg[g] = v.x; lg[g] = v.y;
            }
            float mtot = MFLOOR;
            #pragma unroll
            for (int g = 0; g < 8; ++g) mtot = fmaxf(mtot, mg[g]);
            float eg[8], ltot = 0.f;
            #pragma unroll
            for (int g = 0; g < 8; ++g) {
                eg[g] = __builtin_amdgcn_exp2f(mg[g] - mtot);  // finite args, no NaN
                ltot += eg[g] * lg[g];
            }
            const float inv = (ltot > 0.f) ? (1.0f / ltot) : 0.f;
            const int sw = swz(row);
            float acc[4] = {0.f, 0.f, 0.f, 0.f};
            #pragma unroll
            for (int g = 0; g < 8; ++g) {
                const float* Pg = Mbase + g * 2048 + row * 64;
                #pragma unroll
                for (int j = 0; j < 4; ++j)
                    acc[j] += eg[g] * Pg[(d0 + j) ^ sw];
            }
            float4 outv;
            outv.x = acc[0] * inv; outv.y = acc[1] * inv;
            outv.z = acc[2] * inv; outv.w = acc[3] * inv;
            *reinterpret_cast<float4*>(O + bo + (size_t)(q0 + 32 * qsub + row) * DK + d0) = outv;
        }
        __syncthreads();  // protect Ks/Vts/Ml before next q-tile restages
    }
}

extern "C" void kernel_launch(void* const* d_in, const int* in_sizes, int n_in,
                              void* d_out, int out_size, void* d_ws, size_t ws_size,
                              hipStream_t stream) {
    (void)in_sizes; (void)n_in; (void)out_size; (void)ws_size;
    const float* q = (const float*)d_in[0];
    const float* k = (const float*)d_in[1];
    const float* v = (const float*)d_in[2];
    float* o = (float*)d_out;
    short* wk = (short*)d_ws;                       // 4 MB bf16 K tiles
    short* wv = wk + (size_t)8 * 64 * 4096;         // 4 MB bf16 V^T tiles

    hipLaunchKernelGGL(prep_kernel, dim3(64, 8), dim3(256), 0, stream, k, v, wk, wv);
    hipLaunchKernelGGL(attn_kernel, dim3(32, 8), dim3(1024), 0, stream, q, o, wk, wv);
}

// Round 16
// 56.733 us; speedup vs baseline: 1.2505x; 1.2505x over previous
//
#include <hip/hip_runtime.h>
#include <hip/hip_bf16.h>
#include <stdint.h>

#define S_LEN 4096
#define DK    64
#define BQ    64
#define BK    64

typedef __bf16 bf16x8  __attribute__((ext_vector_type(8)));
typedef float  f32x16  __attribute__((ext_vector_type(16)));

__device__ __forceinline__ short f2bf(float f) {
    union { __bf16 h; short s; } u; u.h = (__bf16)f; return u.s;
}
__device__ __forceinline__ short4 cvt4(float4 f) {
    short4 s; s.x = f2bf(f.x); s.y = f2bf(f.y); s.z = f2bf(f.z); s.w = f2bf(f.w); return s;
}

__device__ __forceinline__ uint32_t cvtpk_bf16(float lo, float hi) {
    uint32_t d;
    asm("v_cvt_pk_bf16_f32 %0, %1, %2" : "=&v"(d) : "v"(lo), "v"(hi));
    return d;
}
__device__ __forceinline__ void plswap(uint32_t& a, uint32_t& b) {
    asm("v_permlane32_swap_b32 %0, %1" : "+v"(a), "+v"(b));
}

// global -> LDS direct 16B/lane (LDS dest = wave-uniform base + lane*16).
__device__ __forceinline__ void gload_lds16(const void* g, void* l) {
    auto gp = reinterpret_cast<const uint32_t __attribute__((address_space(1)))*>(
        reinterpret_cast<uintptr_t>(g));
    auto lp = reinterpret_cast<uint32_t __attribute__((address_space(3)))*>(
        reinterpret_cast<uintptr_t>(l));
    __builtin_amdgcn_global_load_lds(gp, lp, 16, 0, 0);
}

// conflict-free chunk swizzle: rows {j,j+8,j+16,j+24} land on distinct chunks
__device__ __forceinline__ int swz(int row) {
    return ((row ^ (row >> 3)) & 7) << 3;
}

// ---- prep: K -> bf16 swizzled [b][tile][row][col^swz]; V -> bf16 transposed
// [b][tile][d][key^swz]. One (b,tile) per block.
__global__ __launch_bounds__(256) void prep_kernel(
    const float* __restrict__ K, const float* __restrict__ V,
    short* __restrict__ WK, short* __restrict__ WV)
{
    const int t = blockIdx.x, b = blockIdx.y;
    const int tid = threadIdx.x;
    const size_t ibase = ((size_t)b * S_LEN + (size_t)t * 64) * DK;
    const size_t obase = ((size_t)b * 64 + t) * 4096;
    const int r0 = tid >> 4;          // 0..15
    const int c0 = (tid & 15) * 4;    // 0..60

    #pragma unroll
    for (int i = 0; i < 4; ++i) {
        const int row = r0 + 16 * i;
        const float4 f = *reinterpret_cast<const float4*>(K + ibase + (size_t)row * DK + c0);
        *reinterpret_cast<short4*>(WK + obase + row * 64 + (c0 ^ swz(row))) = cvt4(f);
    }
    float4 vf[4];
    #pragma unroll
    for (int j = 0; j < 4; ++j)
        vf[j] = *reinterpret_cast<const float4*>(V + ibase + (size_t)(4 * r0 + j) * DK + c0);
    #pragma unroll
    for (int jj = 0; jj < 4; ++jj) {
        const int d = c0 + jj;
        short4 sp;
        sp.x = f2bf(reinterpret_cast<const float*>(&vf[0])[jj]);
        sp.y = f2bf(reinterpret_cast<const float*>(&vf[1])[jj]);
        sp.z = f2bf(reinterpret_cast<const float*>(&vf[2])[jj]);
        sp.w = f2bf(reinterpret_cast<const float*>(&vf[3])[jj]);
        *reinterpret_cast<short4*>(WV + obase + d * 64 + ((4 * r0) ^ swz(d))) = sp;
    }
}

// ---- main: flash attention, causal, scale=1/64 * log2(e) (exp2 domain).
// R13 structure: 256 blocks x 512 threads, 8 waves = 4 grp x 2 qsub, full
// 64-key tiles per wave, swapped QK^T, in-register P, quad double-buffer,
// ONE barrier per quad-iter. NEW: speculative exp2 — for p>0, P is computed
// directly off the MFMA output with the OLD running max (clamped at 2^60);
// the max/sum reduction and the (rare) rescale run in the shadow of PV, and
// the fixup is a post-PV multiply (exactly equivalent: pe*alpha = exp2(s-m_new)).
__global__ __launch_bounds__(512, 2) void attn_kernel(
    const float* __restrict__ Q, float* __restrict__ O,
    const short* __restrict__ WK, const short* __restrict__ WV)
{
    __shared__ __align__(16) short Ks[2][16384];   // [buf][tile*4096 + row*64 + col^swz]
    __shared__ __align__(16) short Vts[2][16384];  // [buf][tile*4096 + d*64 + key^swz]
    __shared__ float2 Ml[4][2][32];                // [grp][qsub][qrow] {m,l} (log2)

    const int tid  = threadIdx.x;
    const int wave = tid >> 6;
    const int lane = tid & 63;
    const int q32  = lane & 31;
    const int hi   = lane >> 5;
    const int hi4  = hi * 4;
    const int hi8  = hi * 8;
    const int grp  = wave & 3;   // key-split group: computes k-tile 4p+grp
    const int qsub = wave >> 2;  // 32-row q sub-tile

    const int batch = blockIdx.y;
    const size_t bo = (size_t)batch * S_LEN * DK;
    const short* WKb = WK + (size_t)batch * 262144;
    const short* WVb = WV + (size_t)batch * 262144;

    auto stage_quad = [&](int quad, int buf) {
        const char* gk = (const char*)(WKb + (size_t)quad * 16384) + wave * 1024 + lane * 16;
        const char* gv = (const char*)(WVb + (size_t)quad * 16384) + wave * 1024 + lane * 16;
        char* lk = (char*)(&Ks[buf][0]) + wave * 1024;
        char* lv = (char*)(&Vts[buf][0]) + wave * 1024;
        #pragma unroll
        for (int i = 0; i < 4; ++i) {
            gload_lds16(gk + i * 8192, lk + i * 8192);
            gload_lds16(gv + i * 8192, lv + i * 8192);
        }
    };

    const float NEG_INF = -__builtin_inff();
    const float MFLOOR  = -1e38f;
    const float QSCALE  = 0.015625f * 1.44269504088896341f;  // 1/64 * log2(e)
    const int swz0 = swz(q32);        // rows q32 and 32+q32
    const int swz1 = swz(32 + q32);

    #pragma unroll 1
    for (int qi = 0; qi < 2; ++qi) {
        const int qb = qi ? (int)blockIdx.x : 63 - (int)blockIdx.x;
        const int q0 = qb * BQ;
        const int ntiles = qb + 1;
        const int nquads = (ntiles + 3) >> 2;
        const int qrow   = q0 + 32 * qsub + q32;

        // Q fragments (B operand), scale folded
        bf16x8 qf[4];
        {
            const float* Qr = Q + bo + (size_t)qrow * DK;
            #pragma unroll
            for (int s = 0; s < 4; ++s) {
                const float4 a = *reinterpret_cast<const float4*>(Qr + 16 * s + hi8);
                const float4 b = *reinterpret_cast<const float4*>(Qr + 16 * s + hi8 + 4);
                qf[s][0] = (__bf16)(a.x * QSCALE); qf[s][1] = (__bf16)(a.y * QSCALE);
                qf[s][2] = (__bf16)(a.z * QSCALE); qf[s][3] = (__bf16)(a.w * QSCALE);
                qf[s][4] = (__bf16)(b.x * QSCALE); qf[s][5] = (__bf16)(b.y * QSCALE);
                qf[s][6] = (__bf16)(b.z * QSCALE); qf[s][7] = (__bf16)(b.w * QSCALE);
            }
        }

        float m_run = MFLOOR, l_run = 0.f;
        f32x16 oa0, oa1;  // O[q=crow(r,hi)][d = 32c + q32]
        #pragma unroll
        for (int r = 0; r < 16; ++r) { oa0[r] = 0.f; oa1[r] = 0.f; }

        stage_quad(0, 0);
        __syncthreads();

        for (int p = 0; p < nquads; ++p) {
            const int kt = 4 * p + grp;
            const bool pf = (p + 1 < nquads);
            if (pf) stage_quad(p + 1, (p + 1) & 1);  // in flight across compute

            const short* Kt = &Ks[p & 1][grp * 4096];
            const short* Vt = &Vts[p & 1][grp * 4096];

            if (kt < ntiles) {
                // ---- S^T = K Q (swapped): lane owns full row q32
                f32x16 sa0, sa1;
                #pragma unroll
                for (int r = 0; r < 16; ++r) { sa0[r] = 0.f; sa1[r] = 0.f; }
                __builtin_amdgcn_s_setprio(1);
                #pragma unroll
                for (int s = 0; s < 4; ++s) {
                    const int col = 16 * s + hi8;
                    const bf16x8 kf0 = *reinterpret_cast<const bf16x8*>(&Kt[q32 * 64 + (col ^ swz0)]);
                    const bf16x8 kf1 = *reinterpret_cast<const bf16x8*>(&Kt[(32 + q32) * 64 + (col ^ swz1)]);
                    sa0 = __builtin_amdgcn_mfma_f32_32x32x16_bf16(kf0, qf[s], sa0, 0, 0, 0);
                    sa1 = __builtin_amdgcn_mfma_f32_32x32x16_bf16(kf1, qf[s], sa1, 0, 0, 0);
                }
                __builtin_amdgcn_s_setprio(0);

                // ---- causal mask (diag tile only; wave-uniform branch)
                if (kt == qb) {
                    const int keybase = kt * BK + hi4;
                    #pragma unroll
                    for (int r = 0; r < 16; ++r) {
                        const int kl = (r & 3) + 8 * (r >> 2);
                        if (keybase + kl > qrow) sa0[r] = NEG_INF;
                        if (keybase + kl + 32 > qrow) sa1[r] = NEG_INF;
                    }
                }

                if (p == 0) {
                    // ---- classic first tile: establish finite m_run
                    float ma[4] = {NEG_INF, NEG_INF, NEG_INF, NEG_INF};
                    #pragma unroll
                    for (int r = 0; r < 16; ++r) {
                        ma[r & 3] = fmaxf(ma[r & 3], sa0[r]);
                        ma[r & 3] = fmaxf(ma[r & 3], sa1[r]);
                    }
                    float mt = fmaxf(fmaxf(ma[0], ma[1]), fmaxf(ma[2], ma[3]));
                    mt = fmaxf(mt, __shfl_xor(mt, 32));
                    m_run = fmaxf(m_run, mt);  // finite: diag row always has its diagonal

                    float pp[4] = {0.f, 0.f, 0.f, 0.f};
                    #pragma unroll
                    for (int r = 0; r < 16; ++r) {
                        sa0[r] = __builtin_amdgcn_exp2f(sa0[r] - m_run); pp[r & 3] += sa0[r];
                        sa1[r] = __builtin_amdgcn_exp2f(sa1[r] - m_run); pp[r & 3] += sa1[r];
                    }
                    float ps = (pp[0] + pp[1]) + (pp[2] + pp[3]);
                    ps += __shfl_xor(ps, 32);
                    l_run += ps;

                    __builtin_amdgcn_s_setprio(1);
                    #pragma unroll
                    for (int c = 0; c < 2; ++c) {
                        const f32x16& sp = c ? sa1 : sa0;
                        #pragma unroll
                        for (int s2 = 0; s2 < 2; ++s2) {
                            uint32_t a0 = cvtpk_bf16(sp[8*s2+0], sp[8*s2+1]);
                            uint32_t a1 = cvtpk_bf16(sp[8*s2+2], sp[8*s2+3]);
                            uint32_t b0 = cvtpk_bf16(sp[8*s2+4], sp[8*s2+5]);
                            uint32_t b1 = cvtpk_bf16(sp[8*s2+6], sp[8*s2+7]);
                            plswap(a0, b0);
                            plswap(a1, b1);
                            union { uint32_t u[4]; bf16x8 v; } pw;
                            pw.u[0] = a0; pw.u[1] = a1; pw.u[2] = b0; pw.u[3] = b1;
                            const int vcol = 32 * c + 16 * s2 + hi8;
                            const bf16x8 vf0 = *reinterpret_cast<const bf16x8*>(&Vt[q32 * 64 + (vcol ^ swz0)]);
                            const bf16x8 vf1 = *reinterpret_cast<const bf16x8*>(&Vt[(32 + q32) * 64 + (vcol ^ swz1)]);
                            oa0 = __builtin_amdgcn_mfma_f32_32x32x16_bf16(pw.v, vf0, oa0, 0, 0, 0);
                            oa1 = __builtin_amdgcn_mfma_f32_32x32x16_bf16(pw.v, vf1, oa1, 0, 0, 0);
                        }
                    }
                    __builtin_amdgcn_s_setprio(0);
                } else {
                    // ---- speculative: exp2 with OLD m_run right off the MFMA
                    // (clamped at 2^60); PV immediately; reductions in PV's shadow.
                    #pragma unroll
                    for (int r = 0; r < 16; ++r) {
                        sa0[r] = __builtin_amdgcn_exp2f(fminf(sa0[r] - m_run, 60.f));
                        sa1[r] = __builtin_amdgcn_exp2f(fminf(sa1[r] - m_run, 60.f));
                    }

                    __builtin_amdgcn_s_setprio(1);
                    #pragma unroll
                    for (int c = 0; c < 2; ++c) {
                        const f32x16& sp = c ? sa1 : sa0;
                        #pragma unroll
                        for (int s2 = 0; s2 < 2; ++s2) {
                            uint32_t a0 = cvtpk_bf16(sp[8*s2+0], sp[8*s2+1]);
                            uint32_t a1 = cvtpk_bf16(sp[8*s2+2], sp[8*s2+3]);
                            uint32_t b0 = cvtpk_bf16(sp[8*s2+4], sp[8*s2+5]);
                            uint32_t b1 = cvtpk_bf16(sp[8*s2+6], sp[8*s2+7]);
                            plswap(a0, b0);
                            plswap(a1, b1);
                            union { uint32_t u[4]; bf16x8 v; } pw;
                            pw.u[0] = a0; pw.u[1] = a1; pw.u[2] = b0; pw.u[3] = b1;
                            const int vcol = 32 * c + 16 * s2 + hi8;
                            const bf16x8 vf0 = *reinterpret_cast<const bf16x8*>(&Vt[q32 * 64 + (vcol ^ swz0)]);
                            const bf16x8 vf1 = *reinterpret_cast<const bf16x8*>(&Vt[(32 + q32) * 64 + (vcol ^ swz1)]);
                            oa0 = __builtin_amdgcn_mfma_f32_32x32x16_bf16(pw.v, vf0, oa0, 0, 0, 0);
                            oa1 = __builtin_amdgcn_mfma_f32_32x32x16_bf16(pw.v, vf1, oa1, 0, 0, 0);
                        }
                    }
                    __builtin_amdgcn_s_setprio(0);

                    // ---- shadow reductions on pe (monotone: max pe <-> max s)
                    float mx[4] = {0.f, 0.f, 0.f, 0.f};
                    float pp[4] = {0.f, 0.f, 0.f, 0.f};
                    #pragma unroll
                    for (int r = 0; r < 16; ++r) {
                        mx[r & 3] = fmaxf(mx[r & 3], fmaxf(sa0[r], sa1[r]));
                        pp[r & 3] += sa0[r] + sa1[r];
                    }
                    float pmax = fmaxf(fmaxf(mx[0], mx[1]), fmaxf(mx[2], mx[3]));
                    pmax = fmaxf(pmax, __shfl_xor(pmax, 32));
                    float ps = (pp[0] + pp[1]) + (pp[2] + pp[3]);
                    ps += __shfl_xor(ps, 32);

                    if (!__all(pmax <= 256.f)) {   // 2^THR, THR=8
                        // fixup: post-PV rescale (exactly pe*alpha = exp2(s - m_new))
                        const float mt_rel = fmaxf(__log2f(pmax), 0.f);
                        const float alpha  = __builtin_amdgcn_exp2f(-mt_rel);
                        m_run += mt_rel;
                        l_run = (l_run + ps) * alpha;
                        #pragma unroll
                        for (int r = 0; r < 16; ++r) {
                            const float ar = __shfl(alpha, (r & 3) + 8 * (r >> 2) + hi4);
                            oa0[r] *= ar; oa1[r] *= ar;
                        }
                    } else {
                        l_run += ps;
                    }
                }
            }

            __syncthreads();  // reads done + prefetched quad landed
        }

        // ---- 4-way merge: m,l via Ml; O (f32) via retired K-LDS
        if (hi == 0) Ml[grp][qsub][q32] = make_float2(m_run, l_run);
        float4* Om4 = reinterpret_cast<float4*>(&Ks[0][0]);  // 48KB of 64KB
        if (grp != 0) {
            const int midx = (grp - 1) * 2 + qsub;
            #pragma unroll
            for (int c = 0; c < 2; ++c)
                #pragma unroll
                for (int rq = 0; rq < 4; ++rq) {
                    float4 ov;
                    if (c == 0) { ov.x = oa0[4*rq]; ov.y = oa0[4*rq+1]; ov.z = oa0[4*rq+2]; ov.w = oa0[4*rq+3]; }
                    else        { ov.x = oa1[4*rq]; ov.y = oa1[4*rq+1]; ov.z = oa1[4*rq+2]; ov.w = oa1[4*rq+3]; }
                    Om4[(midx * 8 + c * 4 + rq) * 64 + lane] = ov;
                }
        }
        __syncthreads();
        if (grp == 0) {
            const float* Omf = reinterpret_cast<const float*>(&Ks[0][0]);
            float* Ob = O + bo;
            #pragma unroll
            for (int r = 0; r < 16; ++r) {
                const int row_r = (r & 3) + 8 * (r >> 2) + hi4;
                float mg[4], lg[4];
                #pragma unroll
                for (int g = 0; g < 4; ++g) {
                    const float2 v = Ml[g][qsub][row_r];
                    mg[g] = v.x; lg[g] = v.y;
                }
                const float mtot = fmaxf(fmaxf(mg[0], mg[1]), fmaxf(mg[2], mg[3]));
                float eg[4], ltot = 0.f;
                #pragma unroll
                for (int g = 0; g < 4; ++g) {
                    eg[g] = __builtin_amdgcn_exp2f(mg[g] - mtot);  // finite args
                    ltot += eg[g] * lg[g];
                }
                const float inv = (ltot > 0.f) ? (1.0f / ltot) : 0.f;
                #pragma unroll
                for (int c = 0; c < 2; ++c) {
                    float acc = eg[0] * ((c == 0) ? oa0[r] : oa1[r]);
                    #pragma unroll
                    for (int g = 1; g < 4; ++g) {
                        const int midx = (g - 1) * 2 + qsub;
                        acc += eg[g] * Omf[((midx * 8 + c * 4 + (r >> 2)) * 64 + lane) * 4 + (r & 3)];
                    }
                    Ob[(size_t)(q0 + 32 * qsub + row_r) * DK + 32 * c + q32] = acc * inv;
                }
            }
        }
        __syncthreads();  // protect Ks/Ml before next q-tile restages
    }
}

extern "C" void kernel_launch(void* const* d_in, const int* in_sizes, int n_in,
                              void* d_out, int out_size, void* d_ws, size_t ws_size,
                              hipStream_t stream) {
    (void)in_sizes; (void)n_in; (void)out_size; (void)ws_size;
    const float* q = (const float*)d_in[0];
    const float* k = (const float*)d_in[1];
    const float* v = (const float*)d_in[2];
    float* o = (float*)d_out;
    short* wk = (short*)d_ws;                       // 4 MB bf16 K tiles
    short* wv = wk + (size_t)8 * 64 * 4096;         // 4 MB bf16 V^T tiles

    hipLaunchKernelGGL(prep_kernel, dim3(64, 8), dim3(256), 0, stream, k, v, wk, wv);
    hipLaunchKernelGGL(attn_kernel, dim3(32, 8), dim3(512), 0, stream, q, o, wk, wv);
}